// Round 14
// baseline (28182.092 us; speedup 1.0000x reference)
//
#include <hip/hip_runtime.h>

// RadialNCA — XLA-f32 bit-replication (PASSES at absmax=0.015625).
// NUMERICS FROZEN: per-output op sequence must stay bit-identical:
//   mm1: ascending-k single-acc FMA over (kh,kw,c), c fastest; + b1 add
//   tanh: Eigen/XLA fast-tanh rational (clamp 7.905..., IEEE f32 div, select)
//   mm2: ascending-n single-acc FMA; + b2; 0.5f*delta; + s0; clip
//
// R14: R10 structure (2 px/thread, pinned X, waves_per_eu(4,4)) with the
// weight stream moved from the scalar pipe to the vector pipe.
// Why: weight table = 28.7 KB > 16 KB scalar K$ -> every n-pass misses to
// L2 and lgkmcnt drains stall all waves (the invariant ~45us idle across
// R10/R11/R12). Vector L1 = 32 KB holds the whole table. Force VMEM via
// an opaque-zero VGPR added to the pointer (compiler can't prove uniform
// -> global_load_dwordx4; per-lane-identical addr -> broadcast L1 hit).
// Weights then live in VGPRs; FMA operands all-VGPR. w2 (1KB) stays s_load.

#define BATCH 8
#define HGT 256
#define WID 256
#define NHID 256
#define ALPHA 0.5f

// ws layout (floats): [0, 6291456) state ping buffer; then W1^T (+b1), W2
#define WS_W1T_OFF (BATCH * HGT * WID * 3)
#define WS_W2_OFF  (WS_W1T_OFF + 28 * NHID)

// Exact XLA/Eigen generic_fast_tanh_float
__device__ __forceinline__ float tanh_xla(float x) {
    const float cl = 7.90531110763549805f;
    float xc = fminf(fmaxf(x, -cl), cl);
    float x2 = xc * xc;
    float p = fmaf(x2, -2.76076847742355e-16f, 2.00018790482477e-13f);
    p = fmaf(x2, p, -8.60467152213735e-11f);
    p = fmaf(x2, p, 5.12229709037114e-08f);
    p = fmaf(x2, p, 1.48572235717979e-05f);
    p = fmaf(x2, p, 6.37261928875436e-04f);
    p = fmaf(x2, p, 4.89352455891786e-03f);
    p = xc * p;
    float q = fmaf(x2, 1.19825839466702e-06f, 1.18534705686654e-04f);
    q = fmaf(x2, q, 2.26843463243900e-03f);
    q = fmaf(x2, q, 4.89352518554385e-03f);
    float r = p / q;                       // IEEE f32 div (no fast-math)
    return (fabsf(x) < 0.0004f) ? x : r;
}

// w1t[n][k] = W1[k][n] for k<27; w1t[n][27] = b1[n]; then W2
__global__ __launch_bounds__(256) void nca_prep(const float* __restrict__ W1,
                                                const float* __restrict__ b1,
                                                const float* __restrict__ W2,
                                                float* __restrict__ ws) {
    int n = threadIdx.x;
    float* w1t = ws + WS_W1T_OFF;
#pragma unroll
    for (int k = 0; k < 27; ++k) w1t[n * 28 + k] = W1[k * NHID + n];
    w1t[n * 28 + 27] = b1[n];
    ws[WS_W2_OFF + n] = W2[n];
}

// one mm1 chain for pixel offset P (cols P..P+2), ascending k, c fastest
#define MM1_CHAIN(P, ACC)                                   \
    do {                                                    \
        ACC = fmaf(X[0][0 + P][0], w0.x, ACC);              \
        ACC = fmaf(X[0][0 + P][1], w0.y, ACC);              \
        ACC = fmaf(X[0][0 + P][2], w0.z, ACC);              \
        ACC = fmaf(X[0][1 + P][0], w0.w, ACC);              \
        ACC = fmaf(X[0][1 + P][1], w1.x, ACC);              \
        ACC = fmaf(X[0][1 + P][2], w1.y, ACC);              \
        ACC = fmaf(X[0][2 + P][0], w1.z, ACC);              \
        ACC = fmaf(X[0][2 + P][1], w1.w, ACC);              \
        ACC = fmaf(X[0][2 + P][2], w2v.x, ACC);             \
        ACC = fmaf(X[1][0 + P][0], w2v.y, ACC);             \
        ACC = fmaf(X[1][0 + P][1], w2v.z, ACC);             \
        ACC = fmaf(X[1][0 + P][2], w2v.w, ACC);             \
        ACC = fmaf(X[1][1 + P][0], w3.x, ACC);              \
        ACC = fmaf(X[1][1 + P][1], w3.y, ACC);              \
        ACC = fmaf(X[1][1 + P][2], w3.z, ACC);              \
        ACC = fmaf(X[1][2 + P][0], w3.w, ACC);              \
        ACC = fmaf(X[1][2 + P][1], w4.x, ACC);              \
        ACC = fmaf(X[1][2 + P][2], w4.y, ACC);              \
        ACC = fmaf(X[2][0 + P][0], w4.z, ACC);              \
        ACC = fmaf(X[2][0 + P][1], w4.w, ACC);              \
        ACC = fmaf(X[2][0 + P][2], w5.x, ACC);              \
        ACC = fmaf(X[2][1 + P][0], w5.y, ACC);              \
        ACC = fmaf(X[2][1 + P][1], w5.z, ACC);              \
        ACC = fmaf(X[2][1 + P][2], w5.w, ACC);              \
        ACC = fmaf(X[2][2 + P][0], w6.x, ACC);              \
        ACC = fmaf(X[2][2 + P][1], w6.y, ACC);              \
        ACC = fmaf(X[2][2 + P][2], w6.z, ACC);              \
        ACC = ACC + w6.w; /* + b1[n] */                     \
    } while (0)

__global__ __launch_bounds__(256)
__attribute__((amdgpu_waves_per_eu(4, 4)))
void nca_step(const float* __restrict__ sin,
              float* __restrict__ sout,
              const float* __restrict__ w1t,
              const float* __restrict__ w2,
              const float* __restrict__ b2p) {
    const int gid = blockIdx.x * 256 + threadIdx.x;   // 0..262143, 2 px each
    const int xq = gid & 127;
    const int y  = (gid >> 7) & 255;
    const int b  = gid >> 15;
    const int x0 = xq * 2;

    // neighborhood rows y-1..y+1, cols x0-1..x0+2, 3 channels (36 floats)
    float X[3][4][3];
#pragma unroll
    for (int r = 0; r < 3; ++r) {
        const int yy = y + r - 1;
        const bool yok = (yy >= 0) && (yy < HGT);
        const float* rowp = sin + (((long)b * HGT + (yok ? yy : 0)) * WID) * 3;
#pragma unroll
        for (int cc = 0; cc < 4; ++cc) {
            const int xx = x0 + cc - 1;
            const bool ok = yok && (xx >= 0) && (xx < WID);
            if (ok) {
                X[r][cc][0] = rowp[xx * 3 + 0];
                X[r][cc][1] = rowp[xx * 3 + 1];
                X[r][cc][2] = rowp[xx * 3 + 2];
            } else {
                X[r][cc][0] = 0.f; X[r][cc][1] = 0.f; X[r][cc][2] = 0.f;
            }
        }
    }
    // Pin all 36 staged values in arch VGPRs; forbid remat/sinking.
#pragma unroll
    for (int r = 0; r < 3; ++r)
#pragma unroll
        for (int cc = 0; cc < 4; ++cc)
#pragma unroll
            for (int c = 0; c < 3; ++c)
                asm volatile("" : "+v"(X[r][cc][c]));

    // Opaque zero in a VGPR: defeats uniformity analysis so weight loads
    // go down the VECTOR pipe (global_load_dwordx4 -> 32KB L1, which holds
    // the whole 28.7KB table). Per-lane addresses identical -> broadcast.
    unsigned vz;
    asm volatile("v_mov_b32 %0, 0" : "=v"(vz));
    const float4* __restrict__ wqv =
        (const float4*)((const char*)w1t + vz);   // 7 float4 per n

    float delta0 = 0.f, delta1 = 0.f;

#pragma unroll 2
    for (int n = 0; n < NHID; ++n) {
        const float4 w0  = wqv[n * 7 + 0];
        const float4 w1  = wqv[n * 7 + 1];
        const float4 w2v = wqv[n * 7 + 2];
        const float4 w3  = wqv[n * 7 + 3];
        const float4 w4  = wqv[n * 7 + 4];
        const float4 w5  = wqv[n * 7 + 5];
        const float4 w6  = wqv[n * 7 + 6];
        const float  w2n = w2[n];          // 1KB table: stays scalar (sK$ hit)

        float a0 = 0.f, a1 = 0.f;
        MM1_CHAIN(0, a0);
        MM1_CHAIN(1, a1);
        const float h0 = tanh_xla(a0);
        const float h1 = tanh_xla(a1);
        delta0 = fmaf(h0, w2n, delta0);
        delta1 = fmaf(h1, w2n, delta1);
    }

    const float b2v = b2p[0];
    float* op = sout + (((long)b * HGT + y) * WID + x0) * 3;
    {
        const float s0 = X[1][1][0];
        const float d  = delta0 + b2v;
        const float td = ALPHA * d;
        float pat = s0 + td;
        pat = fminf(fmaxf(pat, 0.f), 1.f);
        op[0] = pat;
        op[1] = X[1][1][1];
        op[2] = X[1][1][2];
    }
    {
        const float s0 = X[1][2][0];
        const float d  = delta1 + b2v;
        const float td = ALPHA * d;
        float pat = s0 + td;
        pat = fminf(fmaxf(pat, 0.f), 1.f);
        op[3] = pat;
        op[4] = X[1][2][1];
        op[5] = X[1][2][2];
    }
}

extern "C" void kernel_launch(void* const* d_in, const int* in_sizes, int n_in,
                              void* d_out, int out_size, void* d_ws, size_t ws_size,
                              hipStream_t stream) {
    const float* state = (const float*)d_in[0];
    const float* W1    = (const float*)d_in[1];
    const float* b1    = (const float*)d_in[2];
    const float* W2    = (const float*)d_in[3];
    const float* b2    = (const float*)d_in[4];

    float* ws_state = (float*)d_ws;
    float* w1t      = ws_state + WS_W1T_OFF;
    float* w2c      = ws_state + WS_W2_OFF;
    float* out      = (float*)d_out;

    nca_prep<<<1, 256, 0, stream>>>(W1, b1, W2, ws_state);

    const int nblocks = (BATCH * HGT * (WID / 2)) / 256;   // 1024

    for (int t = 0; t < 128; ++t) {
        const float* in  = (t == 0) ? state : (((t - 1) & 1) ? out : ws_state);
        float*       dst = (t & 1) ? out : ws_state;
        nca_step<<<nblocks, 256, 0, stream>>>(in, dst, w1t, w2c, b2);
    }
}

// Round 15
// 16509.740 us; speedup vs baseline: 1.7070x; 1.7070x over previous
//
#include <hip/hip_runtime.h>

// RadialNCA — XLA-f32 bit-replication (PASSES at absmax=0.015625).
// NUMERICS FROZEN: per-output op sequence must stay bit-identical:
//   mm1: ascending-k single-acc FMA over (kh,kw,c), c fastest; + b1 add
//   tanh: Eigen/XLA fast-tanh rational (clamp 7.905..., RN f32 div, select)
//   mm2: ascending-n single-acc FMA; + b2; 0.5f*delta; + s0; clip
//
// R15: R10 base (2 px/thread, pinned X, SMEM weights, waves_per_eu(4,4))
// with the IEEE division replaced by the Markstein correctly-rounded
// sequence: rcp + 2xNR + mul + residual-fma + correction-fma.
// For tanh's operand range (q in [4.89e-3, 1.31], |p| <= ~|q|; no denorms,
// no extreme exponents) this returns RN(p/q) bit-identical to '/', but
// avoids the compiler div expansion's two s_setreg MODE toggles (VALU
// pipeline drains ~15cyc each) present in every config since R6 — the
// shared ~150us plateau's best-fitting hidden cost.

#define BATCH 8
#define HGT 256
#define WID 256
#define NHID 256
#define ALPHA 0.5f

// ws layout (floats): [0, 6291456) state ping buffer; then W1^T (+b1), W2
#define WS_W1T_OFF (BATCH * HGT * WID * 3)
#define WS_W2_OFF  (WS_W1T_OFF + 28 * NHID)

// Correctly-rounded f32 divide for normal-range operands (Markstein).
// RN(p/q) for q in [4.89e-3, 1.31], |p| <= 1.31: bit-identical to IEEE '/'.
__device__ __forceinline__ float div_rn(float p, float q) {
    float r = __builtin_amdgcn_rcpf(q);          // ~1ulp seed
    r = fmaf(fmaf(-q, r, 1.0f), r, r);           // NR1
    r = fmaf(fmaf(-q, r, 1.0f), r, r);           // NR2: r ~ 1/q to ~0.5ulp
    float y = p * r;
    float e = fmaf(-q, y, p);                    // exact residual
    return fmaf(e, r, y);                        // final round: RN(p/q)
}

// Exact XLA/Eigen generic_fast_tanh_float (division via div_rn)
__device__ __forceinline__ float tanh_xla(float x) {
    const float cl = 7.90531110763549805f;
    float xc = fminf(fmaxf(x, -cl), cl);
    float x2 = xc * xc;
    float p = fmaf(x2, -2.76076847742355e-16f, 2.00018790482477e-13f);
    p = fmaf(x2, p, -8.60467152213735e-11f);
    p = fmaf(x2, p, 5.12229709037114e-08f);
    p = fmaf(x2, p, 1.48572235717979e-05f);
    p = fmaf(x2, p, 6.37261928875436e-04f);
    p = fmaf(x2, p, 4.89352455891786e-03f);
    p = xc * p;
    float q = fmaf(x2, 1.19825839466702e-06f, 1.18534705686654e-04f);
    q = fmaf(x2, q, 2.26843463243900e-03f);
    q = fmaf(x2, q, 4.89352518554385e-03f);
    float r = div_rn(p, q);                      // == IEEE p/q (RN) in range
    return (fabsf(x) < 0.0004f) ? x : r;
}

// w1t[n][k] = W1[k][n] for k<27; w1t[n][27] = b1[n]; then W2
__global__ __launch_bounds__(256) void nca_prep(const float* __restrict__ W1,
                                                const float* __restrict__ b1,
                                                const float* __restrict__ W2,
                                                float* __restrict__ ws) {
    int n = threadIdx.x;
    float* w1t = ws + WS_W1T_OFF;
#pragma unroll
    for (int k = 0; k < 27; ++k) w1t[n * 28 + k] = W1[k * NHID + n];
    w1t[n * 28 + 27] = b1[n];
    ws[WS_W2_OFF + n] = W2[n];
}

// one mm1 chain for pixel offset P (cols P..P+2), ascending k, c fastest
#define MM1_CHAIN(P, ACC)                                   \
    do {                                                    \
        ACC = fmaf(X[0][0 + P][0], w0.x, ACC);              \
        ACC = fmaf(X[0][0 + P][1], w0.y, ACC);              \
        ACC = fmaf(X[0][0 + P][2], w0.z, ACC);              \
        ACC = fmaf(X[0][1 + P][0], w0.w, ACC);              \
        ACC = fmaf(X[0][1 + P][1], w1.x, ACC);              \
        ACC = fmaf(X[0][1 + P][2], w1.y, ACC);              \
        ACC = fmaf(X[0][2 + P][0], w1.z, ACC);              \
        ACC = fmaf(X[0][2 + P][1], w1.w, ACC);              \
        ACC = fmaf(X[0][2 + P][2], w2v.x, ACC);             \
        ACC = fmaf(X[1][0 + P][0], w2v.y, ACC);             \
        ACC = fmaf(X[1][0 + P][1], w2v.z, ACC);             \
        ACC = fmaf(X[1][0 + P][2], w2v.w, ACC);             \
        ACC = fmaf(X[1][1 + P][0], w3.x, ACC);              \
        ACC = fmaf(X[1][1 + P][1], w3.y, ACC);              \
        ACC = fmaf(X[1][1 + P][2], w3.z, ACC);              \
        ACC = fmaf(X[1][2 + P][0], w3.w, ACC);              \
        ACC = fmaf(X[1][2 + P][1], w4.x, ACC);              \
        ACC = fmaf(X[1][2 + P][2], w4.y, ACC);              \
        ACC = fmaf(X[2][0 + P][0], w4.z, ACC);              \
        ACC = fmaf(X[2][0 + P][1], w4.w, ACC);              \
        ACC = fmaf(X[2][0 + P][2], w5.x, ACC);              \
        ACC = fmaf(X[2][1 + P][0], w5.y, ACC);              \
        ACC = fmaf(X[2][1 + P][1], w5.z, ACC);              \
        ACC = fmaf(X[2][1 + P][2], w5.w, ACC);              \
        ACC = fmaf(X[2][2 + P][0], w6.x, ACC);              \
        ACC = fmaf(X[2][2 + P][1], w6.y, ACC);              \
        ACC = fmaf(X[2][2 + P][2], w6.z, ACC);              \
        ACC = ACC + w6.w; /* + b1[n] */                     \
    } while (0)

__global__ __launch_bounds__(256)
__attribute__((amdgpu_waves_per_eu(4, 4)))
void nca_step(const float* __restrict__ sin,
              float* __restrict__ sout,
              const float* __restrict__ w1t,
              const float* __restrict__ w2,
              const float* __restrict__ b2p) {
    const int gid = blockIdx.x * 256 + threadIdx.x;   // 0..262143, 2 px each
    const int xq = gid & 127;
    const int y  = (gid >> 7) & 255;
    const int b  = gid >> 15;
    const int x0 = xq * 2;

    // neighborhood rows y-1..y+1, cols x0-1..x0+2, 3 channels (36 floats)
    float X[3][4][3];
#pragma unroll
    for (int r = 0; r < 3; ++r) {
        const int yy = y + r - 1;
        const bool yok = (yy >= 0) && (yy < HGT);
        const float* rowp = sin + (((long)b * HGT + (yok ? yy : 0)) * WID) * 3;
#pragma unroll
        for (int cc = 0; cc < 4; ++cc) {
            const int xx = x0 + cc - 1;
            const bool ok = yok && (xx >= 0) && (xx < WID);
            if (ok) {
                X[r][cc][0] = rowp[xx * 3 + 0];
                X[r][cc][1] = rowp[xx * 3 + 1];
                X[r][cc][2] = rowp[xx * 3 + 2];
            } else {
                X[r][cc][0] = 0.f; X[r][cc][1] = 0.f; X[r][cc][2] = 0.f;
            }
        }
    }
    // Pin all 36 staged values in arch VGPRs; forbid remat/sinking.
#pragma unroll
    for (int r = 0; r < 3; ++r)
#pragma unroll
        for (int cc = 0; cc < 4; ++cc)
#pragma unroll
            for (int c = 0; c < 3; ++c)
                asm volatile("" : "+v"(X[r][cc][c]));

    const float4* __restrict__ wq = (const float4*)w1t;   // 7 float4 per n

    float delta0 = 0.f, delta1 = 0.f;

#pragma unroll 2
    for (int n = 0; n < NHID; ++n) {
        // wave-uniform -> s_load_dwordx4; named SSA values live in SGPRs
        const float4 w0  = wq[n * 7 + 0];
        const float4 w1  = wq[n * 7 + 1];
        const float4 w2v = wq[n * 7 + 2];
        const float4 w3  = wq[n * 7 + 3];
        const float4 w4  = wq[n * 7 + 4];
        const float4 w5  = wq[n * 7 + 5];
        const float4 w6  = wq[n * 7 + 6];
        const float  w2n = w2[n];

        float a0 = 0.f, a1 = 0.f;
        MM1_CHAIN(0, a0);
        MM1_CHAIN(1, a1);
        const float h0 = tanh_xla(a0);
        const float h1 = tanh_xla(a1);
        delta0 = fmaf(h0, w2n, delta0);
        delta1 = fmaf(h1, w2n, delta1);
    }

    const float b2v = b2p[0];
    float* op = sout + (((long)b * HGT + y) * WID + x0) * 3;
    {
        const float s0 = X[1][1][0];
        const float d  = delta0 + b2v;
        const float td = ALPHA * d;
        float pat = s0 + td;
        pat = fminf(fmaxf(pat, 0.f), 1.f);
        op[0] = pat;
        op[1] = X[1][1][1];
        op[2] = X[1][1][2];
    }
    {
        const float s0 = X[1][2][0];
        const float d  = delta1 + b2v;
        const float td = ALPHA * d;
        float pat = s0 + td;
        pat = fminf(fmaxf(pat, 0.f), 1.f);
        op[3] = pat;
        op[4] = X[1][2][1];
        op[5] = X[1][2][2];
    }
}

extern "C" void kernel_launch(void* const* d_in, const int* in_sizes, int n_in,
                              void* d_out, int out_size, void* d_ws, size_t ws_size,
                              hipStream_t stream) {
    const float* state = (const float*)d_in[0];
    const float* W1    = (const float*)d_in[1];
    const float* b1    = (const float*)d_in[2];
    const float* W2    = (const float*)d_in[3];
    const float* b2    = (const float*)d_in[4];

    float* ws_state = (float*)d_ws;
    float* w1t      = ws_state + WS_W1T_OFF;
    float* w2c      = ws_state + WS_W2_OFF;
    float* out      = (float*)d_out;

    nca_prep<<<1, 256, 0, stream>>>(W1, b1, W2, ws_state);

    const int nblocks = (BATCH * HGT * (WID / 2)) / 256;   // 1024

    for (int t = 0; t < 128; ++t) {
        const float* in  = (t == 0) ? state : (((t - 1) & 1) ? out : ws_state);
        float*       dst = (t & 1) ? out : ws_state;
        nca_step<<<nblocks, 256, 0, stream>>>(in, dst, w1t, w2c, b2);
    }
}